// Round 8
// baseline (406.137 us; speedup 1.0000x reference)
//
#include <hip/hip_runtime.h>
#include <hip/hip_bf16.h>

typedef unsigned short u16;
typedef __attribute__((ext_vector_type(4))) float f32x4;
typedef __attribute__((ext_vector_type(8))) _Float16 f16x8;
typedef __attribute__((ext_vector_type(4))) _Float16 f16x4;
typedef __attribute__((ext_vector_type(2))) _Float16 h2;

// dims
#define NB 2
#define TT 4096
#define HID 1024
#define NHEAD 16
#define DH 64
#define NHT (NB * NHEAD)          // 32
#define QKV_ELEMS (NHT * TT * DH) // 8388608 per tensor
#define LO_SCALE 2048.0f          // 2^11
#define LO_INV   4.8828125e-4f    // 2^-11
#define MNEG (-1.0e30f)
#define LP 40                     // padded LDS row stride (u16): 80B = 20 banks

union U8 { uint4 u; h2 h[4]; f16x8 v; };

__device__ __forceinline__ f32x4 mf16(f16x8 a, f16x8 b, f32x4 c) {
    return __builtin_amdgcn_mfma_f32_16x16x32_f16(a, b, c, 0, 0, 0);
}

// ---------------------------------------------------------------------------
// Pre-conversion kernels: fp32 -> fp16 hi (+ 2^11*lo)
// ---------------------------------------------------------------------------
__global__ __launch_bounds__(256) void conv_split(
    const float* __restrict__ src, u16* __restrict__ hi, u16* __restrict__ lo, int n4)
{
    int i = blockIdx.x * 256 + threadIdx.x;
    if (i >= n4) return;
    f32x4 x = ((const f32x4*)src)[i];
    f16x4 h, l;
#pragma unroll
    for (int u = 0; u < 4; u++) {
        _Float16 hh = (_Float16)x[u];
        h[u] = hh;
        l[u] = (_Float16)((x[u] - (float)hh) * LO_SCALE);
    }
    ((f16x4*)hi)[i] = h;
    ((f16x4*)lo)[i] = l;
}

__global__ __launch_bounds__(256) void conv_hi(
    const float* __restrict__ src, u16* __restrict__ hi, int n4)
{
    int i = blockIdx.x * 256 + threadIdx.x;
    if (i >= n4) return;
    f32x4 x = ((const f32x4*)src)[i];
    f16x4 h;
#pragma unroll
    for (int u = 0; u < 4; u++) h[u] = (_Float16)x[u];
    ((f16x4*)hi)[i] = h;
}

// ---------------------------------------------------------------------------
// Kernel A16: Q and V projection from pre-converted fp16 inputs.
// LDS tiles padded to stride 40 u16 (conflict-free ds_read_b128 / writes).
// ---------------------------------------------------------------------------
__global__ __launch_bounds__(256) void qv_gemm16(
    const u16* __restrict__ H16,
    const u16* __restrict__ Wq16, const u16* __restrict__ Wv16,
    const float* __restrict__ bq, const float* __restrict__ bv,
    float* __restrict__ qout, u16* __restrict__ vout)
{
    const int z = blockIdx.z;
    const u16* W    = (z == 0) ? Wq16 : Wv16;
    const float* bias = (z == 0) ? bq : bv;

    __shared__ __align__(16) u16 At[128 * LP];
    __shared__ __align__(16) u16 Bt[128 * LP];

    const int tid  = threadIdx.x;
    const int lane = tid & 63;
    const int wid  = tid >> 6;
    const int wm = (wid >> 1) * 64;
    const int wn = (wid & 1) * 64;
    const int bm = blockIdx.x * 128;
    const int bn = blockIdx.y * 128;
    const int l15 = lane & 15, l4 = lane >> 4;

    f32x4 acc[4][4] = {};

    for (int k0 = 0; k0 < 1024; k0 += 32) {
#pragma unroll
        for (int h2i = 0; h2i < 2; h2i++) {
            int c = h2i * 256 + tid;           // 512 16B-chunks per tile
            int row = c >> 2;
            int kc  = (c & 3) * 8;
            *(uint4*)&At[row * LP + kc] = *(const uint4*)&H16[(size_t)(bm + row) * 1024 + k0 + kc];
            *(uint4*)&Bt[row * LP + kc] = *(const uint4*)&W[(size_t)(bn + row) * 1024 + k0 + kc];
        }
        __syncthreads();

        f16x8 aF[4], bF[4];
#pragma unroll
        for (int i = 0; i < 4; i++) {
            aF[i] = *(const f16x8*)&At[(wm + i * 16 + l15) * LP + l4 * 8];
            bF[i] = *(const f16x8*)&Bt[(wn + i * 16 + l15) * LP + l4 * 8];
        }
#pragma unroll
        for (int i = 0; i < 4; i++)
#pragma unroll
            for (int j = 0; j < 4; j++)
                acc[i][j] = mf16(aF[i], bF[j], acc[i][j]);
        __syncthreads();
    }

    float bvj[4];
#pragma unroll
    for (int j = 0; j < 4; j++) bvj[j] = bias[bn + wn + j * 16 + l15];

#pragma unroll
    for (int i = 0; i < 4; i++) {
#pragma unroll
        for (int j = 0; j < 4; j++) {
            int col = bn + wn + j * 16 + l15;
            int hh = col >> 6, dd = col & 63;
#pragma unroll
            for (int r = 0; r < 4; r++) {
                int m = bm + wm + i * 16 + l4 * 4 + r;
                float v = acc[i][j][r] + bvj[j];
                if (z == 0) {
                    qout[(size_t)m * HID + col] = v;
                } else {
                    int nbat = m >> 12, t = m & 4095;
                    _Float16 hv = (_Float16)v;
                    vout[(((size_t)(nbat * NHEAD + hh)) * TT + t) * DH + dd] = *(u16*)&hv;
                }
            }
        }
    }
}

// ---------------------------------------------------------------------------
// Kernel B16: K projection, 2-term fp16 split (hi + 2^11*lo), 3 MFMAs.
// LDS tiles padded to stride 40 u16.
// ---------------------------------------------------------------------------
__global__ __launch_bounds__(256) void k_gemm16(
    const u16* __restrict__ Hh, const u16* __restrict__ Hl,
    const u16* __restrict__ Wkh, const u16* __restrict__ Wkl,
    const float* __restrict__ bk, const float* __restrict__ bq,
    u16* __restrict__ kout, float* __restrict__ norms)
{
    __shared__ __align__(16) u16 Ah[128 * LP];
    __shared__ __align__(16) u16 Al[128 * LP];
    __shared__ __align__(16) u16 Bh[128 * LP];
    __shared__ __align__(16) u16 Bl[128 * LP];

    const int tid  = threadIdx.x;
    const int lane = tid & 63;
    const int wid  = tid >> 6;
    const int wm = (wid >> 1) * 64;
    const int wn = (wid & 1) * 64;
    const int bm = blockIdx.x * 128;
    const int bn = blockIdx.y * 128;
    const int l15 = lane & 15, l4 = lane >> 4;

    f32x4 accM[4][4] = {};
    f32x4 accC[4][4] = {};

    for (int k0 = 0; k0 < 1024; k0 += 32) {
#pragma unroll
        for (int h2i = 0; h2i < 2; h2i++) {
            int c = h2i * 256 + tid;
            int row = c >> 2;
            int kc  = (c & 3) * 8;
            size_t ga = (size_t)(bm + row) * 1024 + k0 + kc;
            size_t gb = (size_t)(bn + row) * 1024 + k0 + kc;
            *(uint4*)&Ah[row * LP + kc] = *(const uint4*)&Hh[ga];
            *(uint4*)&Al[row * LP + kc] = *(const uint4*)&Hl[ga];
            *(uint4*)&Bh[row * LP + kc] = *(const uint4*)&Wkh[gb];
            *(uint4*)&Bl[row * LP + kc] = *(const uint4*)&Wkl[gb];
        }
        __syncthreads();

        f16x8 aH[4], aL[4], bH[4], bL[4];
#pragma unroll
        for (int i = 0; i < 4; i++) {
            int ao = (wm + i * 16 + l15) * LP + l4 * 8;
            int bo = (wn + i * 16 + l15) * LP + l4 * 8;
            aH[i] = *(const f16x8*)&Ah[ao];
            aL[i] = *(const f16x8*)&Al[ao];
            bH[i] = *(const f16x8*)&Bh[bo];
            bL[i] = *(const f16x8*)&Bl[bo];
        }
#pragma unroll
        for (int i = 0; i < 4; i++)
#pragma unroll
            for (int j = 0; j < 4; j++) {
                accM[i][j] = mf16(aH[i], bH[j], accM[i][j]);
                accC[i][j] = mf16(aH[i], bL[j], accC[i][j]);
                accC[i][j] = mf16(aL[i], bH[j], accC[i][j]);
            }
        __syncthreads();
    }

    float bkj[4], bqj[4];
#pragma unroll
    for (int j = 0; j < 4; j++) {
        bkj[j] = bk[bn + wn + j * 16 + l15];
        bqj[j] = bq[bn + wn + j * 16 + l15];
    }

#pragma unroll
    for (int i = 0; i < 4; i++) {
#pragma unroll
        for (int r = 0; r < 4; r++) {
            int m = bm + wm + i * 16 + l4 * 4 + r;
            int nbat = m >> 12, t = m & 4095;
            float sq = 0.f;
#pragma unroll
            for (int j = 0; j < 4; j++) {
                int col = bn + wn + j * 16 + l15;
                int hh = col >> 6, dd = col & 63;
                float kv = accM[i][j][r] + accC[i][j][r] * LO_INV + bkj[j];
                _Float16 hv = (_Float16)kv;
                kout[(((size_t)(nbat * NHEAD + hh)) * TT + t) * DH + dd] = *(u16*)&hv;
                float x = kv + bqj[j];
                sq = fmaf(x, x, sq);
            }
            sq += __shfl_xor(sq, 1);
            sq += __shfl_xor(sq, 2);
            sq += __shfl_xor(sq, 4);
            sq += __shfl_xor(sq, 8);
            if (l15 == 0) {
                int hh = (bn + wn) >> 6;
                norms[((size_t)(nbat * NHEAD + hh)) * TT + t] = sq;
            }
        }
    }
}

// ---------------------------------------------------------------------------
// FALLBACK GEMMs (fp32 staging + convert) — used if ws small.
// ---------------------------------------------------------------------------
__global__ __launch_bounds__(256) void qv_gemm(
    const float* __restrict__ H,
    const float* __restrict__ Wq, const float* __restrict__ Wv,
    const float* __restrict__ bq, const float* __restrict__ bv,
    float* __restrict__ qout, u16* __restrict__ vout)
{
    const int z = blockIdx.z;
    const float* W    = (z == 0) ? Wq : Wv;
    const float* bias = (z == 0) ? bq : bv;

    __shared__ __align__(16) u16 Ah[128 * 32];
    __shared__ __align__(16) u16 Bh[128 * 32];

    const int tid  = threadIdx.x;
    const int lane = tid & 63;
    const int wid  = tid >> 6;
    const int wm = (wid >> 1) * 64;
    const int wn = (wid & 1) * 64;
    const int bm = blockIdx.x * 128;
    const int bn = blockIdx.y * 128;
    const int l15 = lane & 15, l4 = lane >> 4;

    f32x4 acc[4][4] = {};

    for (int k0 = 0; k0 < 1024; k0 += 32) {
#pragma unroll
        for (int it = 0; it < 4; it++) {
            int c = it * 256 + tid;
            int row = c >> 3;
            int col = (c & 7) * 4;
            f32x4 a = *(const f32x4*)&H[(size_t)(bm + row) * 1024 + k0 + col];
            f32x4 b = *(const f32x4*)&W[(size_t)(bn + row) * 1024 + k0 + col];
            f16x4 ah, bh;
#pragma unroll
            for (int u = 0; u < 4; u++) { ah[u] = (_Float16)a[u]; bh[u] = (_Float16)b[u]; }
            *(f16x4*)&Ah[row * 32 + col] = ah;
            *(f16x4*)&Bh[row * 32 + col] = bh;
        }
        __syncthreads();

        f16x8 aF[4], bF[4];
#pragma unroll
        for (int i = 0; i < 4; i++) {
            aF[i] = *(const f16x8*)&Ah[(wm + i * 16 + l15) * 32 + l4 * 8];
            bF[i] = *(const f16x8*)&Bh[(wn + i * 16 + l15) * 32 + l4 * 8];
        }
#pragma unroll
        for (int i = 0; i < 4; i++)
#pragma unroll
            for (int j = 0; j < 4; j++)
                acc[i][j] = mf16(aF[i], bF[j], acc[i][j]);
        __syncthreads();
    }

    float bvj[4];
#pragma unroll
    for (int j = 0; j < 4; j++) bvj[j] = bias[bn + wn + j * 16 + l15];

#pragma unroll
    for (int i = 0; i < 4; i++) {
#pragma unroll
        for (int j = 0; j < 4; j++) {
            int col = bn + wn + j * 16 + l15;
            int hh = col >> 6, dd = col & 63;
#pragma unroll
            for (int r = 0; r < 4; r++) {
                int m = bm + wm + i * 16 + l4 * 4 + r;
                float v = acc[i][j][r] + bvj[j];
                if (z == 0) {
                    qout[(size_t)m * HID + col] = v;
                } else {
                    int nbat = m >> 12, t = m & 4095;
                    _Float16 hv = (_Float16)v;
                    vout[(((size_t)(nbat * NHEAD + hh)) * TT + t) * DH + dd] = *(u16*)&hv;
                }
            }
        }
    }
}

__global__ __launch_bounds__(256) void k_gemm(
    const float* __restrict__ H, const float* __restrict__ Wk,
    const float* __restrict__ bk, const float* __restrict__ bq,
    u16* __restrict__ kout, float* __restrict__ norms)
{
    __shared__ __align__(16) u16 Ah[128 * 32];
    __shared__ __align__(16) u16 Al[128 * 32];
    __shared__ __align__(16) u16 Bh[128 * 32];
    __shared__ __align__(16) u16 Bl[128 * 32];

    const int tid  = threadIdx.x;
    const int lane = tid & 63;
    const int wid  = tid >> 6;
    const int wm = (wid >> 1) * 64;
    const int wn = (wid & 1) * 64;
    const int bm = blockIdx.x * 128;
    const int bn = blockIdx.y * 128;
    const int l15 = lane & 15, l4 = lane >> 4;

    f32x4 accM[4][4] = {};
    f32x4 accC[4][4] = {};

    for (int k0 = 0; k0 < 1024; k0 += 32) {
#pragma unroll
        for (int it = 0; it < 4; it++) {
            int c = it * 256 + tid;
            int row = c >> 3;
            int col = (c & 7) * 4;
            f32x4 a = *(const f32x4*)&H[(size_t)(bm + row) * 1024 + k0 + col];
            f32x4 b = *(const f32x4*)&Wk[(size_t)(bn + row) * 1024 + k0 + col];
            f16x4 ah, al, bh, bl;
#pragma unroll
            for (int u = 0; u < 4; u++) {
                _Float16 hh = (_Float16)a[u];
                ah[u] = hh; al[u] = (_Float16)((a[u] - (float)hh) * LO_SCALE);
                _Float16 g = (_Float16)b[u];
                bh[u] = g; bl[u] = (_Float16)((b[u] - (float)g) * LO_SCALE);
            }
            *(f16x4*)&Ah[row * 32 + col] = ah;
            *(f16x4*)&Al[row * 32 + col] = al;
            *(f16x4*)&Bh[row * 32 + col] = bh;
            *(f16x4*)&Bl[row * 32 + col] = bl;
        }
        __syncthreads();

        f16x8 aH[4], aL[4], bH[4], bL[4];
#pragma unroll
        for (int i = 0; i < 4; i++) {
            int ao = (wm + i * 16 + l15) * 32 + l4 * 8;
            int bo = (wn + i * 16 + l15) * 32 + l4 * 8;
            aH[i] = *(const f16x8*)&Ah[ao];
            aL[i] = *(const f16x8*)&Al[ao];
            bH[i] = *(const f16x8*)&Bh[bo];
            bL[i] = *(const f16x8*)&Bl[bo];
        }
#pragma unroll
        for (int i = 0; i < 4; i++)
#pragma unroll
            for (int j = 0; j < 4; j++) {
                accM[i][j] = mf16(aH[i], bH[j], accM[i][j]);
                accC[i][j] = mf16(aH[i], bL[j], accC[i][j]);
                accC[i][j] = mf16(aL[i], bH[j], accC[i][j]);
            }
        __syncthreads();
    }

    float bkj[4], bqj[4];
#pragma unroll
    for (int j = 0; j < 4; j++) {
        bkj[j] = bk[bn + wn + j * 16 + l15];
        bqj[j] = bq[bn + wn + j * 16 + l15];
    }

#pragma unroll
    for (int i = 0; i < 4; i++) {
#pragma unroll
        for (int r = 0; r < 4; r++) {
            int m = bm + wm + i * 16 + l4 * 4 + r;
            int nbat = m >> 12, t = m & 4095;
            float sq = 0.f;
#pragma unroll
            for (int j = 0; j < 4; j++) {
                int col = bn + wn + j * 16 + l15;
                int hh = col >> 6, dd = col & 63;
                float kv = accM[i][j][r] + accC[i][j][r] * LO_INV + bkj[j];
                _Float16 hv = (_Float16)kv;
                kout[(((size_t)(nbat * NHEAD + hh)) * TT + t) * DH + dd] = *(u16*)&hv;
                float x = kv + bqj[j];
                sq = fmaf(x, x, sq);
            }
            sq += __shfl_xor(sq, 1);
            sq += __shfl_xor(sq, 2);
            sq += __shfl_xor(sq, 4);
            sq += __shfl_xor(sq, 8);
            if (l15 == 0) {
                int hh = (bn + wn) >> 6;
                norms[((size_t)(nbat * NHEAD + hh)) * TT + t] = sq;
            }
        }
    }
}

// ---------------------------------------------------------------------------
// Kernel C: norm-based top-k per 64-token chunk.
// ---------------------------------------------------------------------------
__global__ __launch_bounds__(64) void select_topk(
    const float* __restrict__ norms_in, const float* __restrict__ mask,
    int* __restrict__ gidx, int* __restrict__ lidx)
{
    const int bid = blockIdx.x;
    const int nh = bid >> 6, c = bid & 63;
    const int n = nh >> 4;
    const int tid = threadIdx.x;
    const int tok = c * 64 + tid;

    float nrm = norms_in[(size_t)nh * TT + tok];
    if (nrm != nrm) nrm = 0.f;
    if (mask[(size_t)n * TT + tok] != 0.f) nrm = 0.f;

    __shared__ float norms[64];
    __shared__ int flags[64];
    norms[tid] = nrm;
    __syncthreads();

    int rank = 0;
    for (int j = 0; j < 64; j++) {
        float nj = norms[j];
        rank += (nj < nrm || (nj == nrm && j < tid)) ? 1 : 0;
    }
    int istop = (rank >= 48) ? 1 : 0;
    flags[tid] = istop;
    __syncthreads();

    int pos = 0;
    for (int j = 0; j < tid; j++) pos += istop ? flags[j] : (1 - flags[j]);
    if (istop) gidx[(size_t)nh * 1024 + c * 16 + pos] = tok;
    else       lidx[(size_t)nh * 3072 + c * 48 + pos] = tok;
}

// ---------------------------------------------------------------------------
// Kernel D: BOS token — full UNSCALED attention over all keys; writes t=0.
// ---------------------------------------------------------------------------
__global__ __launch_bounds__(64) void bos_kernel(
    const u16* __restrict__ K, const u16* __restrict__ V,
    const float* __restrict__ mask, float* __restrict__ out)
{
    const int nh = blockIdx.x;
    const int n = nh >> 4, h = nh & 15;
    const int tid = threadIdx.x;
    const size_t base = (size_t)nh * TT * DH;

    float q[64];
    {
        const float* qr = out + ((size_t)n * TT) * HID + h * 64;
#pragma unroll
        for (int i = 0; i < 16; i++) {
            f32x4 v = *(const f32x4*)&qr[i * 4];
#pragma unroll
            for (int u = 0; u < 4; u++) q[i * 4 + u] = v[u];
        }
    }

    float m_ = -1e30f, l_ = 0.f, acc[64];
#pragma unroll
    for (int d = 0; d < 64; d++) acc[d] = 0.f;

    for (int kk = tid; kk < TT; kk += 64) {
        const u16* kr = K + base + (size_t)kk * DH;
        const u16* vr = V + base + (size_t)kk * DH;
        float s = 0.f;
#pragma unroll
        for (int i = 0; i < 8; i++) {
            f16x8 kv = *(const f16x8*)&kr[i * 8];
#pragma unroll
            for (int u = 0; u < 8; u++) s = fmaf(q[i * 8 + u], (float)kv[u], s);
        }
        s += mask[(size_t)n * TT + kk];
        float mn = fmaxf(m_, s);
        float sc = __expf(m_ - mn);
        float p  = __expf(s - mn);
        l_ = l_ * sc + p;
#pragma unroll
        for (int i = 0; i < 8; i++) {
            f16x8 vv = *(const f16x8*)&vr[i * 8];
#pragma unroll
            for (int u = 0; u < 8; u++)
                acc[i * 8 + u] = fmaf(acc[i * 8 + u], sc, p * (float)vv[u]);
        }
        m_ = mn;
    }

    __shared__ float ms[64], ls[64], accs[64][65];
    ms[tid] = m_; ls[tid] = l_;
#pragma unroll
    for (int d = 0; d < 64; d++) accs[tid][d] = acc[d];
    __syncthreads();

    float M = -1e30f;
    for (int j = 0; j < 64; j++) M = fmaxf(M, ms[j]);
    float L = 0.f;
    for (int j = 0; j < 64; j++) L += ls[j] * __expf(ms[j] - M);
    float sum = 0.f;
    for (int j = 0; j < 64; j++) sum = fmaf(accs[j][tid], __expf(ms[j] - M), sum);
    out[((size_t)n * TT) * HID + h * 64 + tid] = sum / L;
}

// ---------------------------------------------------------------------------
// Kernel E (MFMA flash-style): fused selected-global + local attention.
// ---------------------------------------------------------------------------
__global__ __launch_bounds__(256) void attn_kernel(
    const u16* __restrict__ K, const u16* __restrict__ V,
    const int* __restrict__ gidx, const int* __restrict__ lidx,
    const float* __restrict__ mask, float* __restrict__ out)
{
    const int bid = blockIdx.x;
    const int nh = bid >> 6, c = bid & 63;
    const int n = nh >> 4, h = nh & 15;
    const int tid = threadIdx.x;
    const int wid = tid >> 6, lane = tid & 63;
    const int l15 = lane & 15, quad = lane >> 4;
    const size_t kvbase = (size_t)nh * TT * DH;
    const float* maskrow = mask + (size_t)n * TT;

    __shared__ __align__(16) u16 Ks[96 * 72];   // gathered K rows (+pad 8)
    __shared__ __align__(16) u16 Vs[96 * 72];   // gathered V rows
    __shared__ __align__(16) u16 Ps[64 * 104];  // P matrix (A-layout source)
    __shared__ float Ms[96];                    // per-key mask add

    // Q A-frags for this wave's 16-query band: A[m=l15][k=quad*8+j]
    f16x8 aQ[2];
    {
        const float* qrow = out + ((size_t)n * TT + c * 64 + wid * 16 + l15) * HID + h * 64;
#pragma unroll
        for (int kb = 0; kb < 2; kb++) {
            f32x4 x0 = *(const f32x4*)&qrow[kb * 32 + quad * 8];
            f32x4 x1 = *(const f32x4*)&qrow[kb * 32 + quad * 8 + 4];
            f16x8 a;
#pragma unroll
            for (int u = 0; u < 4; u++) { a[u] = (_Float16)x0[u]; a[u + 4] = (_Float16)x1[u]; }
            aQ[kb] = a;
        }
    }

    float m4[4], l4[4];
    f32x4 O[4];
#pragma unroll
    for (int r = 0; r < 4; r++) { m4[r] = MNEG; l4[r] = 0.f; }
#pragma unroll
    for (int j = 0; j < 4; j++) O[j] = (f32x4){0.f, 0.f, 0.f, 0.f};

    auto pass_tiles = [&](int NT, int NK32) {
        f32x4 s[6];
        for (int kt = 0; kt < NT; kt++) {
            f16x8 b0 = *(const f16x8*)&Ks[(kt * 16 + l15) * 72 + quad * 8];
            f16x8 b1 = *(const f16x8*)&Ks[(kt * 16 + l15) * 72 + 32 + quad * 8];
            f32x4 a = {};
            a = mf16(aQ[0], b0, a);
            a = mf16(aQ[1], b1, a);
            float mv = Ms[kt * 16 + l15];
#pragma unroll
            for (int r = 0; r < 4; r++) a[r] = fmaf(a[r], 0.125f, mv);
            s[kt] = a;
        }
        float rmax[4];
#pragma unroll
        for (int r = 0; r < 4; r++) rmax[r] = s[0][r];
        for (int kt = 1; kt < NT; kt++)
#pragma unroll
            for (int r = 0; r < 4; r++) rmax[r] = fmaxf(rmax[r], s[kt][r]);
#pragma unroll
        for (int msk = 1; msk <= 8; msk <<= 1)
#pragma unroll
            for (int r = 0; r < 4; r++) rmax[r] = fmaxf(rmax[r], __shfl_xor(rmax[r], msk));
        float sc[4], rsum[4] = {0.f, 0.f, 0.f, 0.f};
#pragma unroll
        for (int r = 0; r < 4; r++) {
            float mn = fmaxf(m4[r], rmax[r]);
            sc[r] = __expf(m4[r] - mn);
            m4[r] = mn;
        }
        for (int kt = 0; kt < NT; kt++) {
#pragma unroll
            for (int r = 0; r < 4; r++) {
                float p = __expf(s[kt][r] - m4[r]);
                s[kt][r] = p;
                rsum[r] += p;
            }
        }
#pragma unroll
        for (int msk = 1; msk <= 8; msk <<= 1)
#pragma unroll
            for (int r = 0; r < 4; r++) rsum[r] += __shfl_xor(rsum[r], msk);
#pragma unroll
        for (int r = 0; r < 4; r++) l4[r] = fmaf(l4[r], sc[r], rsum[r]);
#pragma unroll
        for (int j = 0; j < 4; j++)
#pragma unroll
            for (int r = 0; r < 4; r++) O[j][r] *= sc[r];
        for (int kt = 0; kt < NT; kt++) {
#pragma unroll
            for (int r = 0; r < 4; r++) {
                _Float16 ph = (_Float16)s[kt][r];
                Ps[(wid * 16 + quad * 4 + r) * 104 + kt * 16 + l15] = *(u16*)&ph;
            }
        }
        __syncthreads();
        for (int kt2 = 0; kt2 < NK32; kt2++) {
            f16x8 aP = *(const f16x8*)&Ps[(wid * 16 + l15) * 104 + kt2 * 32 + quad * 8];
#pragma unroll
            for (int j = 0; j < 4; j++) {
                f16x8 bV;
#pragma unroll
                for (int jj = 0; jj < 8; jj++) {
                    u16 raw = Vs[(kt2 * 32 + quad * 8 + jj) * 72 + j * 16 + l15];
                    bV[jj] = *(_Float16*)&raw;
                }
                O[j] = mf16(aP, bV, O[j]);
            }
        }
        __syncthreads();
    };

    // ================= GLOBAL (selected) pass: 4 tiles (48 + 16 pad) ======
#pragma unroll 1
    for (int it = 0; it < 2; it++) {
        int slot = it * 256 + tid;
        int kk = slot >> 3, ch = slot & 7;
        int tile = kk >> 4;
        int blkw = c - 1 + tile;
        bool valid = (tile < 3) && (blkw >= 0) && (blkw < 64);
        int key = valid ? (gidx[(size_t)nh * 1024 + blkw * 16 + (kk & 15)] & 4095) : 0;
        *(uint4*)&Ks[kk * 72 + ch * 8] = ((const uint4*)(K + kvbase + (size_t)key * DH))[ch];
        *(uint4*)&Vs[kk * 72 + ch * 8] = ((const uint4*)(V + kvbase + (size_t)key * DH))[ch];
        if (ch == 0) Ms[kk] = valid ? maskrow[key] : MNEG;
    }
    __syncthreads();
    pass_tiles(4, 2);

    float mG[4], lG[4];
    f32x4 OG[4];
#pragma unroll
    for (int r = 0; r < 4; r++) { mG[r] = m4[r]; lG[r] = l4[r]; m4[r] = MNEG; l4[r] = 0.f; }
#pragma unroll
    for (int j = 0; j < 4; j++) { OG[j] = O[j]; O[j] = (f32x4){0.f, 0.f, 0.f, 0.f}; }

    // ================= LOCAL pass: key0 mini-tile + 3 x 96-key segments ===
    {
        const u16* K0 = K + kvbase;
        f16x8 b0 = *(const f16x8*)&K0[quad * 8];
        f16x8 b1 = *(const f16x8*)&K0[32 + quad * 8];
        f32x4 a = {};
        a = mf16(aQ[0], b0, a);
        a = mf16(aQ[1], b1, a);
        float mv = (l15 == 0) ? 0.f : MNEG;
        float rmax[4], sc[4], rsum[4] = {0.f, 0.f, 0.f, 0.f};
#pragma unroll
        for (int r = 0; r < 4; r++) {
            a[r] = fmaf(a[r], 0.125f, mv);
            rmax[r] = a[r];
        }
#pragma unroll
        for (int msk = 1; msk <= 8; msk <<= 1)
#pragma unroll
            for (int r = 0; r < 4; r++) rmax[r] = fmaxf(rmax[r], __shfl_xor(rmax[r], msk));
#pragma unroll
        for (int r = 0; r < 4; r++) {
            float mn = fmaxf(m4[r], rmax[r]);
            sc[r] = __expf(m4[r] - mn);
            m4[r] = mn;
            float p = __expf(a[r] - mn);
            a[r] = p;
            rsum[r] = p;
        }
#pragma unroll
        for (int msk = 1; msk <= 8; msk <<= 1)
#pragma unroll
            for (int r = 0; r < 4; r++) rsum[r] += __shfl_xor(rsum[r], msk);
#pragma unroll
        for (int r = 0; r < 4; r++) l4[r] = fmaf(l4[r], sc[r], rsum[r]);
#pragma unroll
        for (int j = 0; j < 4; j++)
#pragma unroll
            for (int r = 0; r < 4; r++) O[j][r] *= sc[r];
#pragma unroll
        for (int r = 0; r < 4; r++) {
            _Float16 ph = (_Float16)a[r];
            int prow = (wid * 16 + quad * 4 + r) * 104;
            Ps[prow + l15] = *(u16*)&ph;
            _Float16 z = (_Float16)0.f;
            Ps[prow + 16 + l15] = *(u16*)&z;
        }
        __syncthreads();
        f16x8 aP = *(const f16x8*)&Ps[(wid * 16 + l15) * 104 + quad * 8];
        const u16* V0 = V + kvbase;
#pragma unroll
        for (int j = 0; j < 4; j++) {
            u16 raw = V0[j * 16 + l15];
            _Float16 v0 = *(_Float16*)&raw;
            f16x8 bV;
#pragma unroll
            for (int u = 0; u < 8; u++) bV[u] = v0;
            O[j] = mf16(aP, bV, O[j]);
        }
        __syncthreads();
    }

    const int bl = c >> 1;
#pragma unroll 1
    for (int segi = 0; segi < 3; segi++) {
        int blkw = bl - 1 + segi;
        bool valid = (blkw >= 0) && (blkw < 32);
#pragma unroll 1
        for (int it = 0; it < 3; it++) {
            int slot = it * 256 + tid;
            int kk = slot >> 3, ch = slot & 7;
            int key = valid ? (lidx[(size_t)nh * 3072 + blkw * 96 + kk] & 4095) : 0;
            *(uint4*)&Ks[kk * 72 + ch * 8] = ((const uint4*)(K + kvbase + (size_t)key * DH))[ch];
            *(uint4*)&Vs[kk * 72 + ch * 8] = ((const uint4*)(V + kvbase + (size_t)key * DH))[ch];
            if (ch == 0) Ms[kk] = valid ? maskrow[key] : MNEG;
        }
        __syncthreads();
        pass_tiles(6, 3);
    }

    // ================= merge (registers only) + store ====================
#pragma unroll
    for (int r = 0; r < 4; r++) {
        int tq = c * 64 + wid * 16 + quad * 4 + r;
        if (tq == 0) continue;
        float lseg = mG[r] + __logf(lG[r]);
        float lsel = m4[r] + __logf(l4[r]);
        float p = 1.f / (1.f + __expf(lseg - lsel));
        float ig = 1.f / lG[r], il = 1.f / l4[r];
        size_t ob = ((size_t)n * TT + tq) * HID + h * 64;
#pragma unroll
        for (int j = 0; j < 4; j++) {
            float cg = OG[j][r] * ig;
            float cl = O[j][r] * il;
            out[ob + j * 16 + l15] = cg + p * (cl - cg);
        }
    }
}

// ---------------------------------------------------------------------------
__global__ void ws_sentinel(float* out, int n, float val) {
    int i = blockIdx.x * 256 + threadIdx.x;
    if (i < n) out[i] = val;
}

// ---------------------------------------------------------------------------
extern "C" void kernel_launch(void* const* d_in, const int* in_sizes, int n_in,
                              void* d_out, int out_size, void* d_ws, size_t ws_size,
                              hipStream_t stream) {
    int iH = 0, iM = 1, iW[3] = {2, 4, 6}, ib[3] = {3, 5, 7};
    {
        int nw = 0, nb2 = 0, seenH = 0, seenM = 0;
        for (int i = 0; i < n_in; i++) {
            int s = in_sizes[i];
            if (s == 8388608 && !seenH) { iH = i; seenH = 1; }
            else if (s == 8192 && !seenM) { iM = i; seenM = 1; }
            else if (s == 1048576 && nw < 3) iW[nw++] = i;
            else if (s == 1024 && nb2 < 3) ib[nb2++] = i;
        }
    }
    const float* H    = (const float*)d_in[iH];
    const float* mask = (const float*)d_in[iM];
    const float* Wq = (const float*)d_in[iW[0]];
    const float* Wk = (const float*)d_in[iW[1]];
    const float* Wv = (const float*)d_in[iW[2]];
    const float* bq = (const float*)d_in[ib[0]];
    const float* bk = (const float*)d_in[ib[1]];
    const float* bv = (const float*)d_in[ib[2]];
    float* out = (float*)d_out;

    const size_t BASE_NEED = (size_t)2 * QKV_ELEMS * 2 + (size_t)NHT * TT * 4
                           + (size_t)NHT * 1024 * 4 + (size_t)NHT * 3072 * 4;
    const size_t EXT_NEED = BASE_NEED + (size_t)2 * QKV_ELEMS * 2
                          + (size_t)4 * 1048576 * 2;
    if (ws_size < BASE_NEED) {
        float val = (float)(ws_size >> 20);
        ws_sentinel<<<(out_size + 255) / 256, 256, 0, stream>>>(out, out_size, val);
        return;
    }

    u16* Kb = (u16*)d_ws;                             // [32][4096][64] fp16
    u16* Vb = Kb + (size_t)QKV_ELEMS;
    float* norms = (float*)(Vb + (size_t)QKV_ELEMS);  // [32][4096] fp32
    int* gidx = (int*)(norms + (size_t)NHT * TT);     // [32][1024]
    int* lidx = gidx + (size_t)NHT * 1024;            // [32][3072]

    if (ws_size >= EXT_NEED) {
        u16* Hh  = (u16*)(lidx + (size_t)NHT * 3072);
        u16* Hl  = Hh + (size_t)QKV_ELEMS;
        u16* Wqh = Hl + (size_t)QKV_ELEMS;
        u16* Wvh = Wqh + 1048576;
        u16* Wkh = Wvh + 1048576;
        u16* Wkl = Wkh + 1048576;

        conv_split<<<8192, 256, 0, stream>>>(H, Hh, Hl, QKV_ELEMS / 4);
        conv_split<<<1024, 256, 0, stream>>>(Wk, Wkh, Wkl, 1048576 / 4);
        conv_hi<<<1024, 256, 0, stream>>>(Wq, Wqh, 1048576 / 4);
        conv_hi<<<1024, 256, 0, stream>>>(Wv, Wvh, 1048576 / 4);
        qv_gemm16<<<dim3(64, 8, 2), 256, 0, stream>>>(Hh, Wqh, Wvh, bq, bv, out, Vb);
        k_gemm16<<<dim3(64, 8), 256, 0, stream>>>(Hh, Hl, Wkh, Wkl, bk, bq, Kb, norms);
    } else {
        qv_gemm<<<dim3(64, 8, 2), 256, 0, stream>>>(H, Wq, Wv, bq, bv, out, Vb);
        k_gemm<<<dim3(64, 8), 256, 0, stream>>>(H, Wk, bk, bq, Kb, norms);
    }
    select_topk<<<NHT * 64, 64, 0, stream>>>(norms, mask, gidx, lidx);
    bos_kernel<<<NHT, 64, 0, stream>>>(Kb, Vb, mask, out);
    attn_kernel<<<NHT * 64, 256, 0, stream>>>(Kb, Vb, gidx, lidx, mask, out);
}